// Round 6
// baseline (3117.986 us; speedup 1.0000x reference)
//
#include <hip/hip_runtime.h>
#include <math.h>

#define N_NODES 100000
#define N_EDGES 1600000
#define ALPHA 0.1f

#define NRANGE 1024              // dst ranges = blocks
#define RSIZE  98                // nodes per range
#define NTILE  3                 // src tiles (3.2MB bf16 each < 4MB XCD L2)
#define TSIZE  33334
#define NPAD   100002
#define NBKT   (NTILE * NRANGE)
#define SORTB  64
#define TILE_U4 200004           // 33334*96B/16
#define SLICE_U4 1563            // ceil(TILE_U4/128)

// barrier workspace layout (ints)
#define TICK_OFF 0               // [8*32]
#define CNT_OFF  256             // [8*32]
#define FLAG_OFF 512             // [8*32]
#define GCNT_OFF 768
#define DUMMY_OFF 770
#define BARWS_INTS 1024

typedef unsigned short u16;
typedef unsigned int u32;

__device__ __forceinline__ float bf2f(u16 u) {
    return __uint_as_float(((u32)u) << 16);
}
__device__ __forceinline__ u16 f2bf(float f) {
    u32 b = __float_as_uint(f);
    b += 0x7fff + ((b >> 16) & 1);
    return (u16)(b >> 16);
}

// ---------------- lin0 ----------------
__global__ __launch_bounds__(256) void lin0_k(const float* __restrict__ x, const float* __restrict__ W0,
                                              const float* __restrict__ b0, u16* __restrict__ x0b,
                                              u16* __restrict__ h0) {
    int t = blockIdx.x * 256 + threadIdx.x;
    if (t >= N_NODES * 48) return;
    int node = t / 48, f = t % 48;
    float v = b0[f]
            + x[node * 3 + 0] * W0[0 * 48 + f]
            + x[node * 3 + 1] * W0[1 * 48 + f]
            + x[node * 3 + 2] * W0[2 * 48 + f];
    v = v > 0.f ? v : 0.f;
    u16 b = f2bf(v);
    x0b[t] = b;
    h0[t] = b;
}

// ---------------- counting sort ----------------
__global__ __launch_bounds__(256) void histA_k(const int* __restrict__ src, const int* __restrict__ dst,
                                               int* __restrict__ blockhist) {
    __shared__ int hist[NBKT];
    for (int i = threadIdx.x; i < NBKT; i += 256) hist[i] = 0;
    __syncthreads();
    for (int e = blockIdx.x * 256 + threadIdx.x; e < N_EDGES; e += SORTB * 256) {
        int b = (src[e] / TSIZE) * NRANGE + (dst[e] / RSIZE);
        atomicAdd(&hist[b], 1);
    }
    __syncthreads();
    for (int i = threadIdx.x; i < NBKT; i += 256) blockhist[blockIdx.x * NBKT + i] = hist[i];
}

__global__ __launch_bounds__(256) void scanS1_k(int* __restrict__ blockhist, int* __restrict__ tot) {
    int b = blockIdx.x * 256 + threadIdx.x;
    int run = 0;
#pragma unroll 8
    for (int blk = 0; blk < SORTB; blk++) {
        int t = blockhist[blk * NBKT + b];
        blockhist[blk * NBKT + b] = run;
        run += t;
    }
    tot[b] = run;
}

__global__ __launch_bounds__(256) void scanS2_k(const int* __restrict__ tot, int* __restrict__ bktptr) {
    __shared__ int sums[256];
    int tid = threadIdx.x;
    int v[NBKT / 256]; int s = 0;
#pragma unroll
    for (int j = 0; j < NBKT / 256; j++) { v[j] = tot[tid * (NBKT / 256) + j]; s += v[j]; }
    sums[tid] = s; __syncthreads();
    for (int off = 1; off < 256; off <<= 1) {
        int t = (tid >= off) ? sums[tid - off] : 0;
        __syncthreads();
        sums[tid] += t;
        __syncthreads();
    }
    int run = (tid > 0) ? sums[tid - 1] : 0;
#pragma unroll
    for (int j = 0; j < NBKT / 256; j++) { bktptr[tid * (NBKT / 256) + j] = run; run += v[j]; }
    if (tid == 255) bktptr[NBKT] = run;
}

__global__ __launch_bounds__(256) void scatB_k(const int* __restrict__ src, const int* __restrict__ dst,
                                               const int* __restrict__ blockhist, const int* __restrict__ bktptr,
                                               u32* __restrict__ edges) {
    __shared__ int cur[NBKT];
    for (int i = threadIdx.x; i < NBKT; i += 256)
        cur[i] = bktptr[i] + blockhist[blockIdx.x * NBKT + i];
    __syncthreads();
    for (int e = blockIdx.x * 256 + threadIdx.x; e < N_EDGES; e += SORTB * 256) {
        int s = src[e], d = dst[e];
        int r = d / RSIZE;
        int b = (s / TSIZE) * NRANGE + r;
        int dl = d - r * RSIZE;
        int pos = atomicAdd(&cur[b], 1);
        edges[pos] = ((u32)s << 8) | (u32)dl;
    }
}

// ---------------- software grid barrier (all 1024 blocks co-resident by construction) ----------------
// two-level: per-XCD counter (128 arrivals) -> global counter (8 leaders). RELAXED atomics (no cache
// ops, preserves warmed L2); explicit __threadfence() only when `fence` (layer boundaries).
__device__ __forceinline__ void gbar(int* __restrict__ barws, int xcc, int ticket, int k, bool fence) {
    __syncthreads();                       // drains vmcnt: block's stores are in L2
    if (threadIdx.x == 0) {
        if (fence) __threadfence();        // wbL2: push dirty lines to coherence point
        __hip_atomic_fetch_add(&barws[CNT_OFF + xcc * 32], 1, __ATOMIC_RELAXED, __HIP_MEMORY_SCOPE_AGENT);
        if (ticket == 0) {
            while (__hip_atomic_load(&barws[CNT_OFF + xcc * 32], __ATOMIC_RELAXED, __HIP_MEMORY_SCOPE_AGENT) < 128 * k)
                __builtin_amdgcn_s_sleep(4);
            __hip_atomic_fetch_add(&barws[GCNT_OFF], 1, __ATOMIC_RELAXED, __HIP_MEMORY_SCOPE_AGENT);
            while (__hip_atomic_load(&barws[GCNT_OFF], __ATOMIC_RELAXED, __HIP_MEMORY_SCOPE_AGENT) < 8 * k)
                __builtin_amdgcn_s_sleep(4);
            __hip_atomic_store(&barws[FLAG_OFF + xcc * 32], k, __ATOMIC_RELAXED, __HIP_MEMORY_SCOPE_AGENT);
        } else {
            while (__hip_atomic_load(&barws[FLAG_OFF + xcc * 32], __ATOMIC_RELAXED, __HIP_MEMORY_SCOPE_AGENT) < k)
                __builtin_amdgcn_s_sleep(4);
        }
    }
    __syncthreads();
    if (fence) __threadfence();            // invL1/L2 on every CU: fresh reads of remote h
}

// ---------------- fused 4-layer + final kernel, phase-locked tiled gather ----------------
__global__ __launch_bounds__(512, 8) void gcn4_k(u16* __restrict__ hA, u16* __restrict__ hB,
                                                 const u32* __restrict__ edges,
                                                 const int* __restrict__ bktptr,
                                                 const u16* __restrict__ x0,
                                                 const float* __restrict__ convW,
                                                 const float* __restrict__ W1,
                                                 const float* __restrict__ b1,
                                                 float4 betas, float* __restrict__ out,
                                                 int* __restrict__ barws) {
    __shared__ float accs[RSIZE * 48];     // 18816 B
    __shared__ int s_info[2];
    int tid = threadIdx.x, wave = tid >> 6, lane = tid & 63;
    int range = blockIdx.x;

    u32 xccr;
    asm volatile("s_getreg_b32 %0, hwreg(HW_REG_XCC_ID)" : "=s"(xccr));
    if (tid == 0) {
        int xc = (int)(xccr & 7u);
        s_info[0] = xc;
        s_info[1] = __hip_atomic_fetch_add(&barws[TICK_OFF + xc * 32], 1, __ATOMIC_RELAXED, __HIP_MEMORY_SCOPE_AGENT);
    }
    __syncthreads();
    int xcc = s_info[0], ticket = s_info[1];
    int kbar = 0;

    int sub = lane >> 3;   // edge in group 0..7
    int fl  = lane & 7;    // dword in row 0..7

    const u16* hin = hA; u16* hout = hB;

    for (int l = 0; l < 4; l++) {
        float beta = (l == 0) ? betas.x : (l == 1) ? betas.y : (l == 2) ? betas.z : betas.w;
        const float* W = convW + l * 2304;
        for (int i = tid; i < RSIZE * 48; i += 512) accs[i] = 0.f;
        __syncthreads();

        for (int tile = 0; tile < NTILE; tile++) {
            // --- warm this XCD's L2 with slice `ticket` of the tile (coalesced stream) ---
            {
                const uint4* tb = (const uint4*)(hin + (size_t)tile * TSIZE * 48);
                int st = ticket * SLICE_U4;
                int en = st + SLICE_U4; if (en > TILE_U4) en = TILE_U4;
                u32 dummy = 0;
                for (int g = st + tid; g < en; g += 512) {
                    uint4 v = tb[g];
                    dummy ^= v.x ^ v.y ^ v.z ^ v.w;
                }
                if (dummy == 0xDEADBEEFu)
                    __hip_atomic_store(&barws[DUMMY_OFF], 1, __ATOMIC_RELAXED, __HIP_MEMORY_SCOPE_AGENT);
            }
            // --- gather this block's bucket for (tile, range): L2-resident rows ---
            int b = tile * NRANGE + range;
            int e0 = bktptr[b], e1 = bktptr[b + 1];
            for (int base = e0 + wave * 16; base < e1; base += 8 * 16) {
#pragma unroll
                for (int g = 0; g < 2; g++) {
                    int idx = base + g * 8 + sub;
                    bool valid = idx < e1;
                    int idxc = valid ? idx : (e1 - 1);
                    u32 p = __builtin_nontemporal_load(&edges[idxc]);
                    int s = (int)(p >> 8);
                    int dl = (int)(p & 255u);
                    const u32* row = (const u32*)(hin + s * 48) + fl;
                    u32 d0 = row[0], d1 = row[8], d2 = row[16];
                    if (valid) {
                        float* arow = accs + dl * 48 + fl * 2;
                        __hip_atomic_fetch_add(&arow[0],  __uint_as_float(d0 << 16),         __ATOMIC_RELAXED, __HIP_MEMORY_SCOPE_WORKGROUP);
                        __hip_atomic_fetch_add(&arow[1],  __uint_as_float(d0 & 0xffff0000u), __ATOMIC_RELAXED, __HIP_MEMORY_SCOPE_WORKGROUP);
                        __hip_atomic_fetch_add(&arow[16], __uint_as_float(d1 << 16),         __ATOMIC_RELAXED, __HIP_MEMORY_SCOPE_WORKGROUP);
                        __hip_atomic_fetch_add(&arow[17], __uint_as_float(d1 & 0xffff0000u), __ATOMIC_RELAXED, __HIP_MEMORY_SCOPE_WORKGROUP);
                        __hip_atomic_fetch_add(&arow[32], __uint_as_float(d2 << 16),         __ATOMIC_RELAXED, __HIP_MEMORY_SCOPE_WORKGROUP);
                        __hip_atomic_fetch_add(&arow[33], __uint_as_float(d2 & 0xffff0000u), __ATOMIC_RELAXED, __HIP_MEMORY_SCOPE_WORKGROUP);
                    }
                }
            }
            if (tile < 2) { kbar++; gbar(barws, xcc, ticket, kbar, false); }  // phase lock, no cache ops
        }
        __syncthreads();   // accs complete

        if (l < 3) {
            // epilogue: t = (1-a)*agg + a*x0; h_out = relu((1-b)*t + b*(t@W))
            for (int i = wave; i < RSIZE; i += 8) {
                int node = range * RSIZE + i;
                if (node < N_NODES && lane < 48) {
                    u16 xb = __builtin_nontemporal_load(&x0[node * 48 + lane]);
                    float t = (1.f - ALPHA) * accs[i * 48 + lane] + ALPHA * bf2f(xb);
                    accs[i * 48 + lane] = t;     // wave-synchronous
                    const float4* t4 = (const float4*)&accs[i * 48];
                    float s2 = 0.f;
#pragma unroll
                    for (int k4 = 0; k4 < 12; k4++) {
                        float4 tv = t4[k4];
                        s2 += tv.x * W[(4 * k4 + 0) * 48 + lane] + tv.y * W[(4 * k4 + 1) * 48 + lane]
                            + tv.z * W[(4 * k4 + 2) * 48 + lane] + tv.w * W[(4 * k4 + 3) * 48 + lane];
                    }
                    float o = (1.f - beta) * t + beta * s2;
                    hout[node * 48 + lane] = f2bf(o > 0.f ? o : 0.f);   // regular store (flushed at barrier)
                }
            }
            kbar++; gbar(barws, xcc, ticket, kbar, true);   // layer boundary: release+acquire
            const u16* tmp = hin; hin = hout; hout = (u16*)tmp;
        } else {
            // final: h = relu(...); out = log_softmax(h @ W1 + b1)
            for (int i = wave; i < RSIZE; i += 8) {
                int node = range * RSIZE + i;
                bool act = node < N_NODES;
                if (act && lane < 48) {
                    u16 xb = __builtin_nontemporal_load(&x0[node * 48 + lane]);
                    float t = (1.f - ALPHA) * accs[i * 48 + lane] + ALPHA * bf2f(xb);
                    accs[i * 48 + lane] = t;
                    const float4* t4 = (const float4*)&accs[i * 48];
                    float s2 = 0.f;
#pragma unroll
                    for (int k4 = 0; k4 < 12; k4++) {
                        float4 tv = t4[k4];
                        s2 += tv.x * W[(4 * k4 + 0) * 48 + lane] + tv.y * W[(4 * k4 + 1) * 48 + lane]
                            + tv.z * W[(4 * k4 + 2) * 48 + lane] + tv.w * W[(4 * k4 + 3) * 48 + lane];
                    }
                    float o = (1.f - beta) * t + beta * s2;
                    accs[i * 48 + lane] = o > 0.f ? o : 0.f;
                }
                float v = -INFINITY;
                if (act && lane < 48) {
                    const float4* t4 = (const float4*)&accs[i * 48];
                    float s = b1[lane];
#pragma unroll
                    for (int k4 = 0; k4 < 12; k4++) {
                        float4 tv = t4[k4];
                        s += tv.x * W1[(4 * k4 + 0) * 48 + lane] + tv.y * W1[(4 * k4 + 1) * 48 + lane]
                           + tv.z * W1[(4 * k4 + 2) * 48 + lane] + tv.w * W1[(4 * k4 + 3) * 48 + lane];
                    }
                    v = s;
                }
                float m = v;
                for (int off2 = 32; off2 >= 1; off2 >>= 1) m = fmaxf(m, __shfl_xor(m, off2));
                float ex = (act && lane < 48) ? expf(v - m) : 0.f;
                float sum = ex;
                for (int off2 = 32; off2 >= 1; off2 >>= 1) sum += __shfl_xor(sum, off2);
                if (act && lane < 48) {
                    float r = v - m - logf(sum);
                    __builtin_nontemporal_store(r, &out[node * 48 + lane]);
                }
            }
        }
    }
}

extern "C" void kernel_launch(void* const* d_in, const int* in_sizes, int n_in,
                              void* d_out, int out_size, void* d_ws, size_t ws_size,
                              hipStream_t stream) {
    const float* x     = (const float*)d_in[0];
    const int*   ei    = (const int*)d_in[1];
    const float* W0    = (const float*)d_in[2];
    const float* b0    = (const float*)d_in[3];
    const float* convW = (const float*)d_in[4];
    const float* W1    = (const float*)d_in[5];
    const float* b1    = (const float*)d_in[6];
    float* out = (float*)d_out;
    const int* src = ei;
    const int* dst = ei + N_EDGES;

    char* ws = (char*)d_ws;
    size_t off = 0;
    u16* x0b    = (u16*)(ws + off);   off += (size_t)N_NODES * 48 * 2;
    off = (off + 255) & ~(size_t)255;
    u16* hA     = (u16*)(ws + off);   off += (size_t)NPAD * 48 * 2;
    off = (off + 255) & ~(size_t)255;
    u16* hB     = (u16*)(ws + off);   off += (size_t)NPAD * 48 * 2;
    off = (off + 255) & ~(size_t)255;
    u32* edges  = (u32*)(ws + off);   off += (size_t)N_EDGES * 4;
    off = (off + 255) & ~(size_t)255;
    int* blockhist = (int*)(ws + off); off += (size_t)SORTB * NBKT * 4;
    off = (off + 255) & ~(size_t)255;
    int* bktptr = (int*)(ws + off);   off += (size_t)(NBKT + 1) * 4;
    off = (off + 255) & ~(size_t)255;
    int* tot    = (int*)(ws + off);   off += (size_t)NBKT * 4;
    off = (off + 255) & ~(size_t)255;
    int* barws  = (int*)(ws + off);   off += (size_t)BARWS_INTS * 4;

    hipMemsetAsync(barws, 0, BARWS_INTS * 4, stream);

    lin0_k<<<18750, 256, 0, stream>>>(x, W0, b0, x0b, hA);
    histA_k<<<SORTB, 256, 0, stream>>>(src, dst, blockhist);
    scanS1_k<<<NBKT / 256, 256, 0, stream>>>(blockhist, tot);
    scanS2_k<<<1, 256, 0, stream>>>(tot, bktptr);
    scatB_k<<<SORTB, 256, 0, stream>>>(src, dst, blockhist, bktptr, edges);

    float4 betas = make_float4(logf(1.5f), logf(1.25f), logf(7.f / 6.f), logf(1.125f));

    gcn4_k<<<NRANGE, 512, 0, stream>>>(hA, hB, edges, bktptr, x0b, convW, W1, b1, betas, out, barws);
}

// Round 7
// 2795.465 us; speedup vs baseline: 1.1154x; 1.1154x over previous
//
#include <hip/hip_runtime.h>
#include <math.h>

#define N_NODES 100000
#define N_EDGES 1600000
#define ALPHA 0.1f

#define NRANGE 1024              // dst ranges = blocks
#define RSIZE  98                // nodes per range
#define NTILE  3                 // src tiles (3.2MB bf16 each < 4MB XCD L2)
#define TSIZE  33334
#define NPAD   100002
#define NBKT   (NTILE * NRANGE)
#define SORTB  64
#define TILE_U4 200004           // 33334*96B/16
#define SLICE_U4 1563            // ceil(TILE_U4/128)

// barrier workspace layout (ints)
#define TICK_OFF 0               // [8*32] per-XCD warm tickets
#define CNT_OFF  256             // [8*32] per-group arrival counters
#define FLAG_OFF 512             // [8*32] per-group release flags
#define GCNT_OFF 768
#define DUMMY_OFF 770
#define BARWS_INTS 1024

typedef unsigned short u16;
typedef unsigned int u32;

__device__ __forceinline__ float bf2f(u16 u) {
    return __uint_as_float(((u32)u) << 16);
}
__device__ __forceinline__ u16 f2bf(float f) {
    u32 b = __float_as_uint(f);
    b += 0x7fff + ((b >> 16) & 1);
    return (u16)(b >> 16);
}

// ---------------- lin0 ----------------
__global__ __launch_bounds__(256) void lin0_k(const float* __restrict__ x, const float* __restrict__ W0,
                                              const float* __restrict__ b0, u16* __restrict__ x0b,
                                              u16* __restrict__ h0) {
    int t = blockIdx.x * 256 + threadIdx.x;
    if (t >= N_NODES * 48) return;
    int node = t / 48, f = t % 48;
    float v = b0[f]
            + x[node * 3 + 0] * W0[0 * 48 + f]
            + x[node * 3 + 1] * W0[1 * 48 + f]
            + x[node * 3 + 2] * W0[2 * 48 + f];
    v = v > 0.f ? v : 0.f;
    u16 b = f2bf(v);
    x0b[t] = b;
    h0[t] = b;
}

// ---------------- counting sort ----------------
__global__ __launch_bounds__(256) void histA_k(const int* __restrict__ src, const int* __restrict__ dst,
                                               int* __restrict__ blockhist) {
    __shared__ int hist[NBKT];
    for (int i = threadIdx.x; i < NBKT; i += 256) hist[i] = 0;
    __syncthreads();
    for (int e = blockIdx.x * 256 + threadIdx.x; e < N_EDGES; e += SORTB * 256) {
        int b = (src[e] / TSIZE) * NRANGE + (dst[e] / RSIZE);
        atomicAdd(&hist[b], 1);
    }
    __syncthreads();
    for (int i = threadIdx.x; i < NBKT; i += 256) blockhist[blockIdx.x * NBKT + i] = hist[i];
}

__global__ __launch_bounds__(256) void scanS1_k(int* __restrict__ blockhist, int* __restrict__ tot) {
    int b = blockIdx.x * 256 + threadIdx.x;
    int run = 0;
#pragma unroll 8
    for (int blk = 0; blk < SORTB; blk++) {
        int t = blockhist[blk * NBKT + b];
        blockhist[blk * NBKT + b] = run;
        run += t;
    }
    tot[b] = run;
}

__global__ __launch_bounds__(256) void scanS2_k(const int* __restrict__ tot, int* __restrict__ bktptr) {
    __shared__ int sums[256];
    int tid = threadIdx.x;
    int v[NBKT / 256]; int s = 0;
#pragma unroll
    for (int j = 0; j < NBKT / 256; j++) { v[j] = tot[tid * (NBKT / 256) + j]; s += v[j]; }
    sums[tid] = s; __syncthreads();
    for (int off = 1; off < 256; off <<= 1) {
        int t = (tid >= off) ? sums[tid - off] : 0;
        __syncthreads();
        sums[tid] += t;
        __syncthreads();
    }
    int run = (tid > 0) ? sums[tid - 1] : 0;
#pragma unroll
    for (int j = 0; j < NBKT / 256; j++) { bktptr[tid * (NBKT / 256) + j] = run; run += v[j]; }
    if (tid == 255) bktptr[NBKT] = run;
}

__global__ __launch_bounds__(256) void scatB_k(const int* __restrict__ src, const int* __restrict__ dst,
                                               const int* __restrict__ blockhist, const int* __restrict__ bktptr,
                                               u32* __restrict__ edges) {
    __shared__ int cur[NBKT];
    for (int i = threadIdx.x; i < NBKT; i += 256)
        cur[i] = bktptr[i] + blockhist[blockIdx.x * NBKT + i];
    __syncthreads();
    for (int e = blockIdx.x * 256 + threadIdx.x; e < N_EDGES; e += SORTB * 256) {
        int s = src[e], d = dst[e];
        int r = d / RSIZE;
        int b = (s / TSIZE) * NRANGE + r;
        int dl = d - r * RSIZE;
        int pos = atomicAdd(&cur[b], 1);
        edges[pos] = ((u32)s << 8) | (u32)dl;
    }
}

// ---------------- relaxed grid barrier: NO cache maintenance (preserves warmed L2) ----------------
// groups of 128 blocks keyed by blockIdx&7 (exact count, deadlock-proof); leader = blockIdx<8.
__device__ __forceinline__ void gbar(int* __restrict__ barws, int grp, bool leader, int k) {
    __syncthreads();                       // drains vmcnt: write-through h stores are globally visible
    if (threadIdx.x == 0) {
        asm volatile("" ::: "memory");
        __hip_atomic_fetch_add(&barws[CNT_OFF + grp * 32], 1, __ATOMIC_RELAXED, __HIP_MEMORY_SCOPE_AGENT);
        if (leader) {
            while (__hip_atomic_load(&barws[CNT_OFF + grp * 32], __ATOMIC_RELAXED, __HIP_MEMORY_SCOPE_AGENT) < 128 * k)
                __builtin_amdgcn_s_sleep(8);
            __hip_atomic_fetch_add(&barws[GCNT_OFF], 1, __ATOMIC_RELAXED, __HIP_MEMORY_SCOPE_AGENT);
            while (__hip_atomic_load(&barws[GCNT_OFF], __ATOMIC_RELAXED, __HIP_MEMORY_SCOPE_AGENT) < 8 * k)
                __builtin_amdgcn_s_sleep(8);
            __hip_atomic_store(&barws[FLAG_OFF + grp * 32], k, __ATOMIC_RELAXED, __HIP_MEMORY_SCOPE_AGENT);
        } else {
            while (__hip_atomic_load(&barws[FLAG_OFF + grp * 32], __ATOMIC_RELAXED, __HIP_MEMORY_SCOPE_AGENT) < k)
                __builtin_amdgcn_s_sleep(8);
        }
        asm volatile("" ::: "memory");
    }
    __syncthreads();
}

// ---------------- fused 4-layer + final, phase-locked warmed-L2 tiled gather ----------------
// 4 distinct h buffers (write-once/read-once => no stale-L2 hazard, no invalidates needed).
// h writes are agent-scope write-through => visible cross-XCD after relaxed barrier.
__global__ __launch_bounds__(512, 8) void gcn4_k(const u16* __restrict__ hA, u16* __restrict__ hB,
                                                 u16* __restrict__ hC, u16* __restrict__ hD,
                                                 const u32* __restrict__ edges,
                                                 const int* __restrict__ bktptr,
                                                 const u16* __restrict__ x0,
                                                 const float* __restrict__ convW,
                                                 const float* __restrict__ W1,
                                                 const float* __restrict__ b1,
                                                 float4 betas, float* __restrict__ out,
                                                 int* __restrict__ barws) {
    __shared__ float accs[RSIZE * 48];     // 18816 B
    __shared__ int s_info[2];
    int tid = threadIdx.x, wave = tid >> 6, lane = tid & 63;
    int range = blockIdx.x;
    int grp = blockIdx.x & 7;
    bool leader = blockIdx.x < 8;

    u32 xccr;
    asm volatile("s_getreg_b32 %0, hwreg(HW_REG_XCC_ID)" : "=s"(xccr));
    if (tid == 0) {
        int xc = (int)(xccr & 7u);
        s_info[0] = __hip_atomic_fetch_add(&barws[TICK_OFF + xc * 32], 1, __ATOMIC_RELAXED, __HIP_MEMORY_SCOPE_AGENT);
    }
    __syncthreads();
    int ticket = s_info[0] & 127;
    int kbar = 0;

    int sub = lane >> 3;   // edge in group 0..7
    int fl  = lane & 7;    // dword in row 0..7

    const u16* bufs[4] = { hA, hB, hC, hD };

    for (int l = 0; l < 4; l++) {
        float beta = (l == 0) ? betas.x : (l == 1) ? betas.y : (l == 2) ? betas.z : betas.w;
        const float* W = convW + l * 2304;
        const u16* hin = bufs[l];
        u32* houtw = (l < 3) ? (u32*)bufs[l + 1] : 0;
        for (int i = tid; i < RSIZE * 48; i += 512) accs[i] = 0.f;
        __syncthreads();

        for (int tile = 0; tile < NTILE; tile++) {
            // --- warm this XCD's L2 with slice `ticket` of the tile (coalesced, cacheable) ---
            {
                const uint4* tb = (const uint4*)(hin + (size_t)tile * TSIZE * 48);
                int st = ticket * SLICE_U4;
                int en = st + SLICE_U4; if (en > TILE_U4) en = TILE_U4;
                u32 dummy = 0;
                for (int g = st + tid; g < en; g += 512) {
                    uint4 v = tb[g];
                    dummy ^= v.x ^ v.y ^ v.z ^ v.w;
                }
                if (dummy == 0xDEADBEEFu)
                    __hip_atomic_store(&barws[DUMMY_OFF], 1, __ATOMIC_RELAXED, __HIP_MEMORY_SCOPE_AGENT);
            }
            // --- gather this block's bucket for (tile, range): rows L2-resident ---
            int b = tile * NRANGE + range;
            int e0 = bktptr[b], e1 = bktptr[b + 1];
            for (int base = e0 + wave * 16; base < e1; base += 8 * 16) {
#pragma unroll
                for (int g = 0; g < 2; g++) {
                    int idx = base + g * 8 + sub;
                    bool valid = idx < e1;
                    int idxc = valid ? idx : (e1 - 1);
                    u32 p = __builtin_nontemporal_load(&edges[idxc]);
                    int s = (int)(p >> 8);
                    int dl = (int)(p & 255u);
                    const u32* row = (const u32*)(hin + s * 48) + fl;
                    u32 d0 = row[0], d1 = row[8], d2 = row[16];
                    if (valid) {
                        float* arow = accs + dl * 48 + fl * 2;
                        __hip_atomic_fetch_add(&arow[0],  __uint_as_float(d0 << 16),         __ATOMIC_RELAXED, __HIP_MEMORY_SCOPE_WORKGROUP);
                        __hip_atomic_fetch_add(&arow[1],  __uint_as_float(d0 & 0xffff0000u), __ATOMIC_RELAXED, __HIP_MEMORY_SCOPE_WORKGROUP);
                        __hip_atomic_fetch_add(&arow[16], __uint_as_float(d1 << 16),         __ATOMIC_RELAXED, __HIP_MEMORY_SCOPE_WORKGROUP);
                        __hip_atomic_fetch_add(&arow[17], __uint_as_float(d1 & 0xffff0000u), __ATOMIC_RELAXED, __HIP_MEMORY_SCOPE_WORKGROUP);
                        __hip_atomic_fetch_add(&arow[32], __uint_as_float(d2 << 16),         __ATOMIC_RELAXED, __HIP_MEMORY_SCOPE_WORKGROUP);
                        __hip_atomic_fetch_add(&arow[33], __uint_as_float(d2 & 0xffff0000u), __ATOMIC_RELAXED, __HIP_MEMORY_SCOPE_WORKGROUP);
                    }
                }
            }
            if (tile < 2) { kbar++; gbar(barws, grp, leader, kbar); }  // phase lock, no cache ops
        }
        __syncthreads();   // accs complete

        if (l < 3) {
            // epilogue: t = (1-a)*agg + a*x0; h = relu((1-b)*t + b*(t@W)); write-through bf16 pairs
            for (int i = wave; i < RSIZE; i += 8) {
                int node = range * RSIZE + i;
                if (node < N_NODES) {
                    if (lane < 48) {
                        u16 xb = __builtin_nontemporal_load(&x0[node * 48 + lane]);
                        float t = (1.f - ALPHA) * accs[i * 48 + lane] + ALPHA * bf2f(xb);
                        accs[i * 48 + lane] = t;     // wave-synchronous
                        const float4* t4 = (const float4*)&accs[i * 48];
                        float s2 = 0.f;
#pragma unroll
                        for (int k4 = 0; k4 < 12; k4++) {
                            float4 tv = t4[k4];
                            s2 += tv.x * W[(4 * k4 + 0) * 48 + lane] + tv.y * W[(4 * k4 + 1) * 48 + lane]
                                + tv.z * W[(4 * k4 + 2) * 48 + lane] + tv.w * W[(4 * k4 + 3) * 48 + lane];
                        }
                        float o = (1.f - beta) * t + beta * s2;
                        accs[i * 48 + lane] = o > 0.f ? o : 0.f;   // wave-synchronous
                    }
                    if (lane < 24) {
                        float a = accs[i * 48 + 2 * lane], c = accs[i * 48 + 2 * lane + 1];
                        u32 w = (u32)f2bf(a) | ((u32)f2bf(c) << 16);
                        __hip_atomic_store(&houtw[node * 24 + lane], w, __ATOMIC_RELAXED, __HIP_MEMORY_SCOPE_AGENT);
                    }
                }
            }
            kbar++; gbar(barws, grp, leader, kbar);   // layer boundary (still relaxed)
        } else {
            // final: h = relu(...); out = log_softmax(h @ W1 + b1)
            for (int i = wave; i < RSIZE; i += 8) {
                int node = range * RSIZE + i;
                bool act = node < N_NODES;
                if (act && lane < 48) {
                    u16 xb = __builtin_nontemporal_load(&x0[node * 48 + lane]);
                    float t = (1.f - ALPHA) * accs[i * 48 + lane] + ALPHA * bf2f(xb);
                    accs[i * 48 + lane] = t;
                    const float4* t4 = (const float4*)&accs[i * 48];
                    float s2 = 0.f;
#pragma unroll
                    for (int k4 = 0; k4 < 12; k4++) {
                        float4 tv = t4[k4];
                        s2 += tv.x * W[(4 * k4 + 0) * 48 + lane] + tv.y * W[(4 * k4 + 1) * 48 + lane]
                            + tv.z * W[(4 * k4 + 2) * 48 + lane] + tv.w * W[(4 * k4 + 3) * 48 + lane];
                    }
                    float o = (1.f - beta) * t + beta * s2;
                    accs[i * 48 + lane] = o > 0.f ? o : 0.f;
                }
                float v = -INFINITY;
                if (act && lane < 48) {
                    const float4* t4 = (const float4*)&accs[i * 48];
                    float s = b1[lane];
#pragma unroll
                    for (int k4 = 0; k4 < 12; k4++) {
                        float4 tv = t4[k4];
                        s += tv.x * W1[(4 * k4 + 0) * 48 + lane] + tv.y * W1[(4 * k4 + 1) * 48 + lane]
                           + tv.z * W1[(4 * k4 + 2) * 48 + lane] + tv.w * W1[(4 * k4 + 3) * 48 + lane];
                    }
                    v = s;
                }
                float m = v;
                for (int off2 = 32; off2 >= 1; off2 >>= 1) m = fmaxf(m, __shfl_xor(m, off2));
                float ex = (act && lane < 48) ? expf(v - m) : 0.f;
                float sum = ex;
                for (int off2 = 32; off2 >= 1; off2 >>= 1) sum += __shfl_xor(sum, off2);
                if (act && lane < 48) {
                    float r = v - m - logf(sum);
                    __builtin_nontemporal_store(r, &out[node * 48 + lane]);
                }
            }
        }
    }
}

extern "C" void kernel_launch(void* const* d_in, const int* in_sizes, int n_in,
                              void* d_out, int out_size, void* d_ws, size_t ws_size,
                              hipStream_t stream) {
    const float* x     = (const float*)d_in[0];
    const int*   ei    = (const int*)d_in[1];
    const float* W0    = (const float*)d_in[2];
    const float* b0    = (const float*)d_in[3];
    const float* convW = (const float*)d_in[4];
    const float* W1    = (const float*)d_in[5];
    const float* b1    = (const float*)d_in[6];
    float* out = (float*)d_out;
    const int* src = ei;
    const int* dst = ei + N_EDGES;

    char* ws = (char*)d_ws;
    size_t off = 0;
    u16* x0b    = (u16*)(ws + off);   off += (size_t)N_NODES * 48 * 2;
    off = (off + 255) & ~(size_t)255;
    u16* hA     = (u16*)(ws + off);   off += (size_t)NPAD * 48 * 2;
    off = (off + 255) & ~(size_t)255;
    u16* hB     = (u16*)(ws + off);   off += (size_t)NPAD * 48 * 2;
    off = (off + 255) & ~(size_t)255;
    u16* hC     = (u16*)(ws + off);   off += (size_t)NPAD * 48 * 2;
    off = (off + 255) & ~(size_t)255;
    u16* hD     = (u16*)(ws + off);   off += (size_t)NPAD * 48 * 2;
    off = (off + 255) & ~(size_t)255;
    u32* edges  = (u32*)(ws + off);   off += (size_t)N_EDGES * 4;
    off = (off + 255) & ~(size_t)255;
    int* blockhist = (int*)(ws + off); off += (size_t)SORTB * NBKT * 4;
    off = (off + 255) & ~(size_t)255;
    int* bktptr = (int*)(ws + off);   off += (size_t)(NBKT + 1) * 4;
    off = (off + 255) & ~(size_t)255;
    int* tot    = (int*)(ws + off);   off += (size_t)NBKT * 4;
    off = (off + 255) & ~(size_t)255;
    int* barws  = (int*)(ws + off);   off += (size_t)BARWS_INTS * 4;

    hipMemsetAsync(barws, 0, BARWS_INTS * 4, stream);

    lin0_k<<<18750, 256, 0, stream>>>(x, W0, b0, x0b, hA);
    histA_k<<<SORTB, 256, 0, stream>>>(src, dst, blockhist);
    scanS1_k<<<NBKT / 256, 256, 0, stream>>>(blockhist, tot);
    scanS2_k<<<1, 256, 0, stream>>>(tot, bktptr);
    scatB_k<<<SORTB, 256, 0, stream>>>(src, dst, blockhist, bktptr, edges);

    float4 betas = make_float4(logf(1.5f), logf(1.25f), logf(7.f / 6.f), logf(1.125f));

    gcn4_k<<<NRANGE, 512, 0, stream>>>(hA, hB, hC, hD, edges, bktptr, x0b, convW, W1, b1, betas, out, barws);
}